// Round 6
// baseline (3886.854 us; speedup 1.0000x reference)
//
#include <hip/hip_runtime.h>

// PropositionVQVAE forward on MI355X — bit-exact numpy-float32 emulation for codes.
// Encoder + VQ dist: f32 sequential-FMA GEMMs with KC=384 panel structure (OpenBLAS
// semantics), numpy scalar pairwise row-sums, fl32 dist ops, first-index argmin.
// Decoder recons: 2-plane split-bf16 MFMA (insensitive; proven R1-R5).

#define BB 16384
#define HH 1024
#define KK 16384
#define LDT 40  // u16 LDS stride for decoder MFMA tiles

typedef unsigned short u16;
typedef short bf16x8 __attribute__((ext_vector_type(8)));
typedef float f32x4 __attribute__((ext_vector_type(4)));

__device__ __forceinline__ u16 f2bf(float x) {
  unsigned u = __float_as_uint(x);
  return (u16)((u + 0x7fffu + ((u >> 16) & 1u)) >> 16);
}
__device__ __forceinline__ float bf2f(u16 h) {
  return __uint_as_float(((unsigned)h) << 16);
}

// ================= exact-np f32 GEMM: C = act(A@W + b) =================
// Per-element: sequential f32 FMA over k ascending within 384-wide K panels;
// panel sums combined with single f32 adds (OpenBLAS sgemm KC=384, alpha=1).
template<bool RELU, bool CONCAT>
__global__ void __launch_bounds__(256) sgemm_np(
    const float* __restrict__ A0, const float* __restrict__ A1, const float* __restrict__ A2,
    const float* __restrict__ W, const float* __restrict__ bias, float* __restrict__ C,
    int M, int N, int K)
{
  __shared__ float As[32][64];
  __shared__ float Bs[32][64];
  const int tid = threadIdx.x;
  const int bm = blockIdx.y * 64, bn = blockIdx.x * 64;
  const int rt = tid >> 4, ct = tid & 15;

  float tot[4][4] = {};
  float pan[4][4] = {};

  const int ra = tid & 63, kq = tid >> 6;        // A staging
  const int kw = tid >> 3, cw = (tid & 7) * 8;   // B staging

  for (int k0 = 0; k0 < K; k0 += 32) {
    {
      int gr = bm + ra, gc = k0 + kq * 8;
      float4 v0, v1;
      if (CONCAT) {
        const float* pp = (gc < 256) ? A0 : (gc < 512 ? A1 : A2);
        v0 = *(const float4*)(pp + (long)gr * 256 + (gc & 255));
        v1 = *(const float4*)(pp + (long)gr * 256 + (gc & 255) + 4);
      } else {
        v0 = *(const float4*)(A0 + (long)gr * K + gc);
        v1 = *(const float4*)(A0 + (long)gr * K + gc + 4);
      }
      int kb = kq * 8;
      As[kb + 0][ra] = v0.x; As[kb + 1][ra] = v0.y; As[kb + 2][ra] = v0.z; As[kb + 3][ra] = v0.w;
      As[kb + 4][ra] = v1.x; As[kb + 5][ra] = v1.y; As[kb + 6][ra] = v1.z; As[kb + 7][ra] = v1.w;
    }
    {
      float4 w0 = *(const float4*)(W + (long)(k0 + kw) * N + bn + cw);
      float4 w1 = *(const float4*)(W + (long)(k0 + kw) * N + bn + cw + 4);
      *(float4*)&Bs[kw][cw] = w0;
      *(float4*)&Bs[kw][cw + 4] = w1;
    }
    __syncthreads();
    #pragma unroll 8
    for (int k = 0; k < 32; k++) {
      float4 a4 = *(const float4*)&As[k][rt * 4];
      float4 b4 = *(const float4*)&Bs[k][ct * 4];
      float a[4] = {a4.x, a4.y, a4.z, a4.w};
      float b[4] = {b4.x, b4.y, b4.z, b4.w};
      #pragma unroll
      for (int i = 0; i < 4; i++)
        #pragma unroll
        for (int j = 0; j < 4; j++)
          pan[i][j] = fmaf(a[i], b[j], pan[i][j]);
    }
    __syncthreads();
    if ((((k0 + 32) % 384) == 0) || (k0 + 32) == K) {
      #pragma unroll
      for (int i = 0; i < 4; i++)
        #pragma unroll
        for (int j = 0; j < 4; j++) {
          tot[i][j] = __fadd_rn(tot[i][j], pan[i][j]);
          pan[i][j] = 0.f;
        }
    }
  }
  #pragma unroll
  for (int i = 0; i < 4; i++) {
    int row = bm + rt * 4 + i;
    #pragma unroll
    for (int j = 0; j < 4; j++) {
      int col = bn + ct * 4 + j;
      float v = __fadd_rn(tot[i][j], bias[col]);
      if (RELU) v = v > 0.f ? v : 0.f;
      C[(long)row * N + col] = v;
    }
  }
}

// ================= numpy pairwise row sum-of-squares (n=256) =================
// Exact numpy scalar spec: 128-block with 8 accumulators + fixed tree; 256 = pw128+pw128.
__device__ __forceinline__ float pw128_sq(const float* __restrict__ a) {
  float r[8];
  #pragma unroll
  for (int j = 0; j < 8; j++) r[j] = __fmul_rn(a[j], a[j]);
  for (int i = 8; i < 128; i += 8)
    #pragma unroll
    for (int j = 0; j < 8; j++)
      r[j] = __fadd_rn(r[j], __fmul_rn(a[i + j], a[i + j]));
  return __fadd_rn(
      __fadd_rn(__fadd_rn(r[0], r[1]), __fadd_rn(r[2], r[3])),
      __fadd_rn(__fadd_rn(r[4], r[5]), __fadd_rn(r[6], r[7])));
}
__global__ void __launch_bounds__(256) rowsq_np(
    const float* __restrict__ X, float* __restrict__ out)
{
  int row = blockIdx.x * 256 + threadIdx.x;
  const float* a = X + (long)row * 256;
  out[row] = __fadd_rn(pw128_sq(a), pw128_sq(a + 128));
}

// ================= VQ distance + per-tile argmin (f32 exact) =================
// dist = fl(fl(z_sq + cb_sq) - 2*dot), dot = sequential f32 FMA over k=0..255.
__global__ void __launch_bounds__(256) vqdist(
    const float* __restrict__ Z, const float* __restrict__ CB,
    const float* __restrict__ zsq, const float* __restrict__ cbsq,
    float* __restrict__ pv, int* __restrict__ pi)
{
  __shared__ float Zt[32][68];
  __shared__ float Ct[32][68];
  __shared__ float bval[64][17];
  __shared__ int bidx[64][17];
  const int tid = threadIdx.x;
  const int bm = blockIdx.y * 64;   // rows
  const int bn = blockIdx.x * 64;   // codes
  const int rq = tid >> 4, cq = tid & 15;
  const int sr = tid >> 2, skq = (tid & 3) * 8;

  float acc[4][4] = {};

  for (int k0 = 0; k0 < 256; k0 += 32) {
    {
      const float4* zp = (const float4*)(Z + (long)(bm + sr) * 256 + k0 + skq);
      float4 a0 = zp[0], a1 = zp[1];
      Zt[skq + 0][sr] = a0.x; Zt[skq + 1][sr] = a0.y; Zt[skq + 2][sr] = a0.z; Zt[skq + 3][sr] = a0.w;
      Zt[skq + 4][sr] = a1.x; Zt[skq + 5][sr] = a1.y; Zt[skq + 6][sr] = a1.z; Zt[skq + 7][sr] = a1.w;
      const float4* cp = (const float4*)(CB + (long)(bn + sr) * 256 + k0 + skq);
      float4 c0 = cp[0], c1 = cp[1];
      Ct[skq + 0][sr] = c0.x; Ct[skq + 1][sr] = c0.y; Ct[skq + 2][sr] = c0.z; Ct[skq + 3][sr] = c0.w;
      Ct[skq + 4][sr] = c1.x; Ct[skq + 5][sr] = c1.y; Ct[skq + 6][sr] = c1.z; Ct[skq + 7][sr] = c1.w;
    }
    __syncthreads();
    #pragma unroll 8
    for (int k = 0; k < 32; k++) {
      float4 zv = *(const float4*)&Zt[k][rq * 4];
      float4 cv = *(const float4*)&Ct[k][cq * 4];
      float z[4] = {zv.x, zv.y, zv.z, zv.w};
      float c[4] = {cv.x, cv.y, cv.z, cv.w};
      #pragma unroll
      for (int i = 0; i < 4; i++)
        #pragma unroll
        for (int j = 0; j < 4; j++)
          acc[i][j] = fmaf(z[i], c[j], acc[i][j]);
    }
    __syncthreads();
  }

  #pragma unroll
  for (int i = 0; i < 4; i++) {
    int lrow = rq * 4 + i;
    float zs = zsq[bm + lrow];
    float bv = 3.4e38f; int bi = 0;
    #pragma unroll
    for (int j = 0; j < 4; j++) {       // codes ascend with j -> strict < = first index
      int code = bn + cq * 4 + j;
      float t1 = __fadd_rn(zs, cbsq[code]);
      float d  = __fsub_rn(t1, __fmul_rn(2.0f, acc[i][j]));
      if (d < bv) { bv = d; bi = code; }
    }
    bval[lrow][cq] = bv; bidx[lrow][cq] = bi;
  }
  __syncthreads();
  if (tid < 64) {
    float bv = 3.4e38f; int bi = 0;
    for (int q = 0; q < 16; q++) {      // codes ascend with q -> strict <
      float v = bval[tid][q];
      if (v < bv) { bv = v; bi = bidx[tid][q]; }
    }
    pv[(long)blockIdx.x * BB + bm + tid] = bv;
    pi[(long)blockIdx.x * BB + bm + tid] = bi;
  }
}

__global__ void __launch_bounds__(256) vq_merge3(
    const float* __restrict__ pv, const int* __restrict__ pi, float* __restrict__ codesf)
{
  int row = blockIdx.x * 256 + threadIdx.x;
  float bv = 3.4e38f; int bi = 0;
  for (int t = 0; t < 256; t++) {       // tiles ascend -> strict < = first index
    float v = pv[(long)t * BB + row];
    if (v < bv) { bv = v; bi = pi[(long)t * BB + row]; }
  }
  codesf[row] = (float)bi;
}

// ================= loss + scalars =================
__global__ void __launch_bounds__(256) zq_loss(
    const float* __restrict__ codesf, const float* __restrict__ cb,
    const float* __restrict__ Z, float* __restrict__ accum)
{
  long i4 = (long)blockIdx.x * 256 + threadIdx.x;
  int row = (int)(i4 >> 6);
  int c = (int)(i4 & 63) * 4;
  int code = ((int)codesf[row]) & (KK - 1);
  float4 q = *(const float4*)(cb + (long)code * 256 + c);
  float4 z = *(const float4*)(Z + (long)row * 256 + c);
  float dx = q.x - z.x, dy = q.y - z.y, dz = q.z - z.z, dw = q.w - z.w;
  float s = dx * dx + dy * dy + dz * dz + dw * dw;
  #pragma unroll
  for (int m = 32; m > 0; m >>= 1) s += __shfl_down(s, m);
  __shared__ float wsum[4];
  int lane = threadIdx.x & 63, w = threadIdx.x >> 6;
  if (lane == 0) wsum[w] = s;
  __syncthreads();
  if (threadIdx.x == 0) atomicAdd(accum, wsum[0] + wsum[1] + wsum[2] + wsum[3]);
}

__global__ void write_scalars(const float* __restrict__ accum, float* __restrict__ o)
{
  float m = *accum * (1.0f / (16384.0f * 256.0f));
  o[0] = m; o[1] = 0.25f * m; o[2] = 1.25f * m;
}

__global__ void init_k(float* accum) { *accum = 0.f; }

// ================= decoder: 2-plane split-bf16 MFMA =================
__global__ void __launch_bounds__(256) transpose_split2(
    const float* __restrict__ W, u16* __restrict__ p0, u16* __restrict__ p1, int Kd, int N)
{
  __shared__ float tile[32][33];
  int tx = threadIdx.x, ty = threadIdx.y;
  int n0 = blockIdx.x * 32, k0 = blockIdx.y * 32;
  #pragma unroll
  for (int j = 0; j < 32; j += 8)
    tile[ty + j][tx] = W[(long)(k0 + ty + j) * N + n0 + tx];
  __syncthreads();
  #pragma unroll
  for (int j = 0; j < 32; j += 8) {
    float v = tile[tx][ty + j];
    u16 h = f2bf(v);
    long o = (long)(n0 + ty + j) * Kd + k0 + tx;
    p0[o] = h; p1[o] = f2bf(v - bf2f(h));
  }
}

template<bool RELU, int ASRC, int EPI>
__global__ void __launch_bounds__(256) gemm_dec(
    const float* __restrict__ A0, const float* __restrict__ A1,
    const u16* __restrict__ Bp0, const u16* __restrict__ Bp1,
    const float* __restrict__ bias, float* __restrict__ C,
    int M, int N, int Kd)
{
  __shared__ u16 SA0[128 * LDT];
  __shared__ u16 SA1[128 * LDT];
  __shared__ u16 SB0[128 * LDT];
  __shared__ u16 SB1[128 * LDT];

  const int tid = threadIdx.x;
  const int lane = tid & 63;
  const int wid = tid >> 6;
  const int bm = blockIdx.y * 128, bn = blockIdx.x * 128;
  const int wr = (wid >> 1) * 64, wc = (wid & 1) * 64;
  const int lr = lane & 15;
  const int lg = lane >> 4;
  const int lk = lg * 8;

  f32x4 acc[4][4] = {};

  const int arow = tid >> 3;
  const int ac4 = (tid & 7) * 4;
  const int brow = tid >> 1;
  const int bko = (tid & 1) * 16;

  for (int k0 = 0; k0 < Kd; k0 += 32) {
    #pragma unroll
    for (int rr = 0; rr < 128; rr += 32) {
      int r = arow + rr;
      int gr = bm + r, gc = k0 + ac4;
      float4 v;
      if (ASRC == 2) {
        int code = ((int)A1[gr]) & (KK - 1);
        v = *(const float4*)(A0 + (long)code * 256 + gc);
      } else {
        v = *(const float4*)(A0 + (long)gr * Kd + gc);
      }
      u16 h0 = f2bf(v.x), h1 = f2bf(v.y), h2 = f2bf(v.z), h3 = f2bf(v.w);
      u16 l0 = f2bf(v.x - bf2f(h0)), l1 = f2bf(v.y - bf2f(h1));
      u16 l2 = f2bf(v.z - bf2f(h2)), l3 = f2bf(v.w - bf2f(h3));
      uint2 hp; hp.x = (unsigned)h0 | ((unsigned)h1 << 16); hp.y = (unsigned)h2 | ((unsigned)h3 << 16);
      uint2 lp; lp.x = (unsigned)l0 | ((unsigned)l1 << 16); lp.y = (unsigned)l2 | ((unsigned)l3 << 16);
      *(uint2*)&SA0[r * LDT + ac4] = hp;
      *(uint2*)&SA1[r * LDT + ac4] = lp;
    }
    {
      long bo = (long)(bn + brow) * Kd + k0 + bko;
      *(uint4*)&SB0[brow * LDT + bko] = *(const uint4*)(Bp0 + bo);
      *(uint4*)&SB0[brow * LDT + bko + 8] = *(const uint4*)(Bp0 + bo + 8);
      *(uint4*)&SB1[brow * LDT + bko] = *(const uint4*)(Bp1 + bo);
      *(uint4*)&SB1[brow * LDT + bko + 8] = *(const uint4*)(Bp1 + bo + 8);
    }
    __syncthreads();

    bf16x8 a0[4], a1[4], b0[4], b1[4];
    #pragma unroll
    for (int m = 0; m < 4; m++) {
      a0[m] = *(const bf16x8*)&SA0[(wr + m * 16 + lr) * LDT + lk];
      a1[m] = *(const bf16x8*)&SA1[(wr + m * 16 + lr) * LDT + lk];
    }
    #pragma unroll
    for (int n = 0; n < 4; n++) {
      b0[n] = *(const bf16x8*)&SB0[(wc + n * 16 + lr) * LDT + lk];
      b1[n] = *(const bf16x8*)&SB1[(wc + n * 16 + lr) * LDT + lk];
    }
    #pragma unroll
    for (int m = 0; m < 4; m++)
      #pragma unroll
      for (int n = 0; n < 4; n++) {
        acc[m][n] = __builtin_amdgcn_mfma_f32_16x16x32_bf16(a0[m], b0[n], acc[m][n], 0, 0, 0);
        acc[m][n] = __builtin_amdgcn_mfma_f32_16x16x32_bf16(a0[m], b1[n], acc[m][n], 0, 0, 0);
        acc[m][n] = __builtin_amdgcn_mfma_f32_16x16x32_bf16(a1[m], b0[n], acc[m][n], 0, 0, 0);
      }
    __syncthreads();
  }

  #pragma unroll
  for (int m = 0; m < 4; m++)
    #pragma unroll
    for (int n = 0; n < 4; n++) {
      int col = bn + wc + n * 16 + lr;
      float bv = bias[col];
      #pragma unroll
      for (int r = 0; r < 4; r++) {
        int row = bm + wr + m * 16 + lg * 4 + r;
        float v = acc[m][n][r] + bv;
        if (RELU) v = fmaxf(v, 0.f);
        if (EPI == 1) {
          int seg = col >> 8;
          C[(long)seg * M * 256 + (long)row * 256 + (col & 255)] = v;
        } else {
          C[(long)row * N + col] = v;
        }
      }
    }
}

extern "C" void kernel_launch(void* const* d_in, const int* in_sizes, int n_in,
                              void* d_out, int out_size, void* d_ws, size_t ws_size,
                              hipStream_t stream)
{
  (void)in_sizes; (void)n_in; (void)out_size; (void)ws_size;
  const float* subj = (const float*)d_in[0];
  const float* rel_ = (const float*)d_in[1];
  const float* obj  = (const float*)d_in[2];
  const float* ew1  = (const float*)d_in[3];
  const float* eb1  = (const float*)d_in[4];
  const float* ew2  = (const float*)d_in[5];
  const float* eb2  = (const float*)d_in[6];
  const float* ew3  = (const float*)d_in[7];
  const float* eb3  = (const float*)d_in[8];
  const float* cb   = (const float*)d_in[9];
  const float* dw1  = (const float*)d_in[10];
  const float* db1  = (const float*)d_in[11];
  const float* dw2  = (const float*)d_in[12];
  const float* db2  = (const float*)d_in[13];
  const float* dw3  = (const float*)d_in[14];
  const float* db3  = (const float*)d_in[15];
  float* out = (float*)d_out;

  char* p = (char*)d_ws;
  auto take = [&](size_t bytes) { char* q = p; p += (bytes + 255) & ~(size_t)255; return q; };

  float* accum = (float*)take(256);
  float* zsq  = (float*)take((size_t)BB * 4);
  float* cbsq = (float*)take((size_t)KK * 4);
  u16* x1p0 = (u16*)take((size_t)256 * HH * 2); u16* x1p1 = (u16*)take((size_t)256 * HH * 2);
  u16* x2p0 = (u16*)take((size_t)HH * HH * 2);  u16* x2p1 = (u16*)take((size_t)HH * HH * 2);
  u16* x3p0 = (u16*)take((size_t)HH * 768 * 2); u16* x3p1 = (u16*)take((size_t)HH * 768 * 2);
  float* Z  = (float*)take((size_t)BB * 256 * 4);
  float* H1 = (float*)take((size_t)BB * HH * 4);  // later: pv/pi partials, then D2
  float* H2 = (float*)take((size_t)BB * HH * 4);  // later: D1
  // Peak ws ~159 MB.

  float* pv = (float*)H1;                       // 16.7 MB
  int*   pi = (int*)(H1 + (size_t)256 * BB);    // 16.7 MB (H1 dead after enc2-read)
  float* D1 = H2;                               // H2 dead after enc3-read
  float* D2 = H1;                               // pv/pi dead after merge

  float* codesf = out + (size_t)3 * BB * 256;
  float* scalars = out + (size_t)3 * BB * 256 + BB;

  init_k<<<1, 1, 0, stream>>>(accum);

  transpose_split2<<<dim3(HH / 32, 256 / 32), dim3(32, 8), 0, stream>>>(dw1, x1p0, x1p1, 256, HH);
  transpose_split2<<<dim3(HH / 32, HH / 32), dim3(32, 8), 0, stream>>>(dw2, x2p0, x2p1, HH, HH);
  transpose_split2<<<dim3(768 / 32, HH / 32), dim3(32, 8), 0, stream>>>(dw3, x3p0, x3p1, HH, 768);

  // encoder — bit-exact np-f32 semantics
  sgemm_np<true, true><<<dim3(HH / 64, BB / 64), 256, 0, stream>>>(
      subj, rel_, obj, ew1, eb1, H1, BB, HH, 768);
  sgemm_np<true, false><<<dim3(HH / 64, BB / 64), 256, 0, stream>>>(
      H1, nullptr, nullptr, ew2, eb2, H2, BB, HH, HH);
  sgemm_np<false, false><<<dim3(256 / 64, BB / 64), 256, 0, stream>>>(
      H2, nullptr, nullptr, ew3, eb3, Z, BB, 256, HH);

  // row sums of squares — exact numpy pairwise trees
  rowsq_np<<<BB / 256, 256, 0, stream>>>(Z, zsq);
  rowsq_np<<<KK / 256, 256, 0, stream>>>(cb, cbsq);

  // f32-exact distance + argmin
  vqdist<<<dim3(KK / 64, BB / 64), 256, 0, stream>>>(Z, cb, zsq, cbsq, pv, pi);
  vq_merge3<<<BB / 256, 256, 0, stream>>>(pv, pi, codesf);

  zq_loss<<<(BB * 256) / 1024, 256, 0, stream>>>(codesf, cb, Z, accum);
  write_scalars<<<1, 1, 0, stream>>>(accum, scalars);

  // decoder
  gemm_dec<true, 2, 0><<<dim3(HH / 128, BB / 128), 256, 0, stream>>>(
      cb, codesf, x1p0, x1p1, db1, D1, BB, HH, 256);
  gemm_dec<true, 0, 0><<<dim3(HH / 128, BB / 128), 256, 0, stream>>>(
      D1, nullptr, x2p0, x2p1, db2, D2, BB, HH, HH);
  gemm_dec<false, 0, 1><<<dim3(768 / 128, BB / 128), 256, 0, stream>>>(
      D2, nullptr, x3p0, x3p1, db3, out, BB, 768, HH);
}

// Round 9
// 3020.714 us; speedup vs baseline: 1.2867x; 1.2867x over previous
//
#include <hip/hip_runtime.h>

// PropositionVQVAE forward on MI355X — bit-exact numpy-float32 emulation for codes.
// R7: 8x8 micro-tile (128x128 blocks) for vqdist + sgemm_np; math order unchanged.
// Decoder recons: 2-plane split-bf16 MFMA.

#define BB 16384
#define HH 1024
#define KK 16384
#define LDT 40   // u16 LDS stride for decoder MFMA tiles
#define LDF 132  // f32 LDS stride for f32 tiles (aligned 16B, low store conflicts)

typedef unsigned short u16;
typedef short bf16x8 __attribute__((ext_vector_type(8)));
typedef float f32x4 __attribute__((ext_vector_type(4)));

__device__ __forceinline__ u16 f2bf(float x) {
  unsigned u = __float_as_uint(x);
  return (u16)((u + 0x7fffu + ((u >> 16) & 1u)) >> 16);
}
__device__ __forceinline__ float bf2f(u16 h) {
  return __uint_as_float(((unsigned)h) << 16);
}

// ================= exact-np f32 GEMM: C = act(A@W + b) =================
// Per-element: sequential f32 FMA over k ascending within 384-wide K panels;
// panel sums combined with single f32 adds (OpenBLAS sgemm KC=384, alpha=1).
// 128x128 tile, 8x8 micro, BK=32.
template<bool RELU, bool CONCAT>
__global__ void __launch_bounds__(256) sgemm_np(
    const float* __restrict__ A0, const float* __restrict__ A1, const float* __restrict__ A2,
    const float* __restrict__ W, const float* __restrict__ bias, float* __restrict__ C,
    int M, int N, int K)
{
  __shared__ float As[32][LDF];
  __shared__ float Bs[32][LDF];
  const int tid = threadIdx.x;
  const int bm = blockIdx.y * 128, bn = blockIdx.x * 128;
  const int rt = tid >> 4, ct = tid & 15;

  float tot[8][8] = {};
  float pan[8][8] = {};

  const int sr = tid >> 3, sk4 = (tid & 7) * 4;   // A staging (transpose)
  const int kr = tid >> 5, cc = (tid & 31) * 4;   // B staging (natural)

  for (int k0 = 0; k0 < K; k0 += 32) {
    #pragma unroll
    for (int rep = 0; rep < 4; rep++) {
      int r = sr + rep * 32;
      int gr = bm + r, gc = k0 + sk4;
      float4 v;
      if (CONCAT) {
        const float* pp = (gc < 256) ? A0 : (gc < 512 ? A1 : A2);
        v = *(const float4*)(pp + (long)gr * 256 + (gc & 255));
      } else {
        v = *(const float4*)(A0 + (long)gr * K + gc);
      }
      As[sk4 + 0][r] = v.x; As[sk4 + 1][r] = v.y; As[sk4 + 2][r] = v.z; As[sk4 + 3][r] = v.w;
      int k = kr + rep * 8;
      *(float4*)&Bs[k][cc] = *(const float4*)(W + (long)(k0 + k) * N + bn + cc);
    }
    __syncthreads();
    #pragma unroll 4
    for (int k = 0; k < 32; k++) {
      float4 a0 = *(const float4*)&As[k][rt * 8];
      float4 a1 = *(const float4*)&As[k][rt * 8 + 4];
      float4 b0 = *(const float4*)&Bs[k][ct * 8];
      float4 b1 = *(const float4*)&Bs[k][ct * 8 + 4];
      float a[8] = {a0.x, a0.y, a0.z, a0.w, a1.x, a1.y, a1.z, a1.w};
      float b[8] = {b0.x, b0.y, b0.z, b0.w, b1.x, b1.y, b1.z, b1.w};
      #pragma unroll
      for (int i = 0; i < 8; i++)
        #pragma unroll
        for (int j = 0; j < 8; j++)
          pan[i][j] = fmaf(a[i], b[j], pan[i][j]);
    }
    __syncthreads();
    if ((((k0 + 32) % 384) == 0) || (k0 + 32) == K) {
      #pragma unroll
      for (int i = 0; i < 8; i++)
        #pragma unroll
        for (int j = 0; j < 8; j++) {
          tot[i][j] = __fadd_rn(tot[i][j], pan[i][j]);
          pan[i][j] = 0.f;
        }
    }
  }
  #pragma unroll
  for (int i = 0; i < 8; i++) {
    int row = bm + rt * 8 + i;
    #pragma unroll
    for (int j = 0; j < 8; j++) {
      int col = bn + ct * 8 + j;
      float v = __fadd_rn(tot[i][j], bias[col]);
      if (RELU) v = v > 0.f ? v : 0.f;
      C[(long)row * N + col] = v;
    }
  }
}

// ================= numpy pairwise row sum-of-squares (n=256) =================
__device__ __forceinline__ float pw128_sq(const float* __restrict__ a) {
  float r[8];
  #pragma unroll
  for (int j = 0; j < 8; j++) r[j] = __fmul_rn(a[j], a[j]);
  for (int i = 8; i < 128; i += 8)
    #pragma unroll
    for (int j = 0; j < 8; j++)
      r[j] = __fadd_rn(r[j], __fmul_rn(a[i + j], a[i + j]));
  return __fadd_rn(
      __fadd_rn(__fadd_rn(r[0], r[1]), __fadd_rn(r[2], r[3])),
      __fadd_rn(__fadd_rn(r[4], r[5]), __fadd_rn(r[6], r[7])));
}
__global__ void __launch_bounds__(256) rowsq_np(
    const float* __restrict__ X, float* __restrict__ out)
{
  int row = blockIdx.x * 256 + threadIdx.x;
  const float* a = X + (long)row * 256;
  out[row] = __fadd_rn(pw128_sq(a), pw128_sq(a + 128));
}

// ================= VQ distance + per-tile argmin (f32 exact) =================
// dist = fl(fl(z_sq + cb_sq) - 2*dot), dot = sequential f32 FMA over k=0..255.
// 128 rows x 128 codes per block, 8x8 micro.
__global__ void __launch_bounds__(256) vqdist(
    const float* __restrict__ Z, const float* __restrict__ CB,
    const float* __restrict__ zsq, const float* __restrict__ cbsq,
    float* __restrict__ pv, int* __restrict__ pi)
{
  __shared__ float Zt[32][LDF];
  __shared__ float Ct[32][LDF];
  const int tid = threadIdx.x;
  const int bm = blockIdx.y * 128;   // rows
  const int bn = blockIdx.x * 128;   // codes
  const int rt = tid >> 4, ct = tid & 15;
  const int sr = tid >> 3, sk4 = (tid & 7) * 4;

  float acc[8][8] = {};

  for (int k0 = 0; k0 < 256; k0 += 32) {
    #pragma unroll
    for (int rep = 0; rep < 4; rep++) {
      int r = sr + rep * 32;
      float4 zv = *(const float4*)(Z + (long)(bm + r) * 256 + k0 + sk4);
      Zt[sk4 + 0][r] = zv.x; Zt[sk4 + 1][r] = zv.y; Zt[sk4 + 2][r] = zv.z; Zt[sk4 + 3][r] = zv.w;
      float4 cv = *(const float4*)(CB + (long)(bn + r) * 256 + k0 + sk4);
      Ct[sk4 + 0][r] = cv.x; Ct[sk4 + 1][r] = cv.y; Ct[sk4 + 2][r] = cv.z; Ct[sk4 + 3][r] = cv.w;
    }
    __syncthreads();
    #pragma unroll 4
    for (int k = 0; k < 32; k++) {
      float4 z0 = *(const float4*)&Zt[k][rt * 8];
      float4 z1 = *(const float4*)&Zt[k][rt * 8 + 4];
      float4 c0 = *(const float4*)&Ct[k][ct * 8];
      float4 c1 = *(const float4*)&Ct[k][ct * 8 + 4];
      float z[8] = {z0.x, z0.y, z0.z, z0.w, z1.x, z1.y, z1.z, z1.w};
      float c[8] = {c0.x, c0.y, c0.z, c0.w, c1.x, c1.y, c1.z, c1.w};
      #pragma unroll
      for (int i = 0; i < 8; i++)
        #pragma unroll
        for (int j = 0; j < 8; j++)
          acc[i][j] = fmaf(z[i], c[j], acc[i][j]);
    }
    __syncthreads();
  }

  // epilogue: per row, f32-exact dist, argmin over this block's 128 codes,
  // first-index tie-break (codes ascend with j and with ct).
  #pragma unroll
  for (int i = 0; i < 8; i++) {
    int grow = bm + rt * 8 + i;
    float zs = zsq[grow];
    float bv = 3.4e38f; int bi = 0x7fffffff;
    #pragma unroll
    for (int j = 0; j < 8; j++) {
      int code = bn + ct * 8 + j;
      float t1 = __fadd_rn(zs, cbsq[code]);
      float d  = __fsub_rn(t1, __fmul_rn(2.0f, acc[i][j]));
      if (d < bv) { bv = d; bi = code; }   // strict <: first index within thread
    }
    #pragma unroll
    for (int s = 1; s < 16; s <<= 1) {     // reduce across 16 ct-lanes
      float ov = __shfl_xor(bv, s);
      int   oi = __shfl_xor(bi, s);
      if (ov < bv || (ov == bv && oi < bi)) { bv = ov; bi = oi; }
    }
    if (ct == 0) {
      pv[(long)blockIdx.x * BB + grow] = bv;
      pi[(long)blockIdx.x * BB + grow] = bi;
    }
  }
}

__global__ void __launch_bounds__(256) vq_merge3(
    const float* __restrict__ pv, const int* __restrict__ pi, float* __restrict__ codesf)
{
  int row = blockIdx.x * 256 + threadIdx.x;
  float bv = 3.4e38f; int bi = 0;
  for (int t = 0; t < 128; t++) {       // tiles ascend -> strict < = first index
    float v = pv[(long)t * BB + row];
    if (v < bv) { bv = v; bi = pi[(long)t * BB + row]; }
  }
  codesf[row] = (float)bi;
}

// ================= loss + scalars =================
__global__ void __launch_bounds__(256) zq_loss(
    const float* __restrict__ codesf, const float* __restrict__ cb,
    const float* __restrict__ Z, float* __restrict__ accum)
{
  long i4 = (long)blockIdx.x * 256 + threadIdx.x;
  int row = (int)(i4 >> 6);
  int c = (int)(i4 & 63) * 4;
  int code = ((int)codesf[row]) & (KK - 1);
  float4 q = *(const float4*)(cb + (long)code * 256 + c);
  float4 z = *(const float4*)(Z + (long)row * 256 + c);
  float dx = q.x - z.x, dy = q.y - z.y, dz = q.z - z.z, dw = q.w - z.w;
  float s = dx * dx + dy * dy + dz * dz + dw * dw;
  #pragma unroll
  for (int m = 32; m > 0; m >>= 1) s += __shfl_down(s, m);
  __shared__ float wsum[4];
  int lane = threadIdx.x & 63, w = threadIdx.x >> 6;
  if (lane == 0) wsum[w] = s;
  __syncthreads();
  if (threadIdx.x == 0) atomicAdd(accum, wsum[0] + wsum[1] + wsum[2] + wsum[3]);
}

__global__ void write_scalars(const float* __restrict__ accum, float* __restrict__ o)
{
  float m = *accum * (1.0f / (16384.0f * 256.0f));
  o[0] = m; o[1] = 0.25f * m; o[2] = 1.25f * m;
}

__global__ void init_k(float* accum) { *accum = 0.f; }

// ================= decoder: 2-plane split-bf16 MFMA =================
__global__ void __launch_bounds__(256) transpose_split2(
    const float* __restrict__ W, u16* __restrict__ p0, u16* __restrict__ p1, int Kd, int N)
{
  __shared__ float tile[32][33];
  int tx = threadIdx.x, ty = threadIdx.y;
  int n0 = blockIdx.x * 32, k0 = blockIdx.y * 32;
  #pragma unroll
  for (int j = 0; j < 32; j += 8)
    tile[ty + j][tx] = W[(long)(k0 + ty + j) * N + n0 + tx];
  __syncthreads();
  #pragma unroll
  for (int j = 0; j < 32; j += 8) {
    float v = tile[tx][ty + j];
    u16 h = f2bf(v);
    long o = (long)(n0 + ty + j) * Kd + k0 + tx;
    p0[o] = h; p1[o] = f2bf(v - bf2f(h));
  }
}

template<bool RELU, int ASRC, int EPI>
__global__ void __launch_bounds__(256) gemm_dec(
    const float* __restrict__ A0, const float* __restrict__ A1,
    const u16* __restrict__ Bp0, const u16* __restrict__ Bp1,
    const float* __restrict__ bias, float* __restrict__ C,
    int M, int N, int Kd)
{
  __shared__ u16 SA0[128 * LDT];
  __shared__ u16 SA1[128 * LDT];
  __shared__ u16 SB0[128 * LDT];
  __shared__ u16 SB1[128 * LDT];

  const int tid = threadIdx.x;
  const int lane = tid & 63;
  const int wid = tid >> 6;
  const int bm = blockIdx.y * 128, bn = blockIdx.x * 128;
  const int wr = (wid >> 1) * 64, wc = (wid & 1) * 64;
  const int lr = lane & 15;
  const int lg = lane >> 4;
  const int lk = lg * 8;

  f32x4 acc[4][4] = {};

  const int arow = tid >> 3;
  const int ac4 = (tid & 7) * 4;
  const int brow = tid >> 1;
  const int bko = (tid & 1) * 16;

  for (int k0 = 0; k0 < Kd; k0 += 32) {
    #pragma unroll
    for (int rr = 0; rr < 128; rr += 32) {
      int r = arow + rr;
      int gr = bm + r, gc = k0 + ac4;
      float4 v;
      if (ASRC == 2) {
        int code = ((int)A1[gr]) & (KK - 1);
        v = *(const float4*)(A0 + (long)code * 256 + gc);
      } else {
        v = *(const float4*)(A0 + (long)gr * Kd + gc);
      }
      u16 h0 = f2bf(v.x), h1 = f2bf(v.y), h2 = f2bf(v.z), h3 = f2bf(v.w);
      u16 l0 = f2bf(v.x - bf2f(h0)), l1 = f2bf(v.y - bf2f(h1));
      u16 l2 = f2bf(v.z - bf2f(h2)), l3 = f2bf(v.w - bf2f(h3));
      uint2 hp; hp.x = (unsigned)h0 | ((unsigned)h1 << 16); hp.y = (unsigned)h2 | ((unsigned)h3 << 16);
      uint2 lp; lp.x = (unsigned)l0 | ((unsigned)l1 << 16); lp.y = (unsigned)l2 | ((unsigned)l3 << 16);
      *(uint2*)&SA0[r * LDT + ac4] = hp;
      *(uint2*)&SA1[r * LDT + ac4] = lp;
    }
    {
      long bo = (long)(bn + brow) * Kd + k0 + bko;
      *(uint4*)&SB0[brow * LDT + bko] = *(const uint4*)(Bp0 + bo);
      *(uint4*)&SB0[brow * LDT + bko + 8] = *(const uint4*)(Bp0 + bo + 8);
      *(uint4*)&SB1[brow * LDT + bko] = *(const uint4*)(Bp1 + bo);
      *(uint4*)&SB1[brow * LDT + bko + 8] = *(const uint4*)(Bp1 + bo + 8);
    }
    __syncthreads();

    bf16x8 a0[4], a1[4], b0[4], b1[4];
    #pragma unroll
    for (int m = 0; m < 4; m++) {
      a0[m] = *(const bf16x8*)&SA0[(wr + m * 16 + lr) * LDT + lk];
      a1[m] = *(const bf16x8*)&SA1[(wr + m * 16 + lr) * LDT + lk];
    }
    #pragma unroll
    for (int n = 0; n < 4; n++) {
      b0[n] = *(const bf16x8*)&SB0[(wc + n * 16 + lr) * LDT + lk];
      b1[n] = *(const bf16x8*)&SB1[(wc + n * 16 + lr) * LDT + lk];
    }
    #pragma unroll
    for (int m = 0; m < 4; m++)
      #pragma unroll
      for (int n = 0; n < 4; n++) {
        acc[m][n] = __builtin_amdgcn_mfma_f32_16x16x32_bf16(a0[m], b0[n], acc[m][n], 0, 0, 0);
        acc[m][n] = __builtin_amdgcn_mfma_f32_16x16x32_bf16(a0[m], b1[n], acc[m][n], 0, 0, 0);
        acc[m][n] = __builtin_amdgcn_mfma_f32_16x16x32_bf16(a1[m], b0[n], acc[m][n], 0, 0, 0);
      }
    __syncthreads();
  }

  #pragma unroll
  for (int m = 0; m < 4; m++)
    #pragma unroll
    for (int n = 0; n < 4; n++) {
      int col = bn + wc + n * 16 + lr;
      float bv = bias[col];
      #pragma unroll
      for (int r = 0; r < 4; r++) {
        int row = bm + wr + m * 16 + lg * 4 + r;
        float v = acc[m][n][r] + bv;
        if (RELU) v = fmaxf(v, 0.f);
        if (EPI == 1) {
          int seg = col >> 8;
          C[(long)seg * M * 256 + (long)row * 256 + (col & 255)] = v;
        } else {
          C[(long)row * N + col] = v;
        }
      }
    }
}

extern "C" void kernel_launch(void* const* d_in, const int* in_sizes, int n_in,
                              void* d_out, int out_size, void* d_ws, size_t ws_size,
                              hipStream_t stream)
{
  (void)in_sizes; (void)n_in; (void)out_size; (void)ws_size;
  const float* subj = (const float*)d_in[0];
  const float* rel_ = (const float*)d_in[1];
  const float* obj  = (const float*)d_in[2];
  const float* ew1  = (const float*)d_in[3];
  const float* eb1  = (const float*)d_in[4];
  const float* ew2  = (const float*)d_in[5];
  const float* eb2  = (const float*)d_in[6];
  const float* ew3  = (const float*)d_in[7];
  const float* eb3  = (const float*)d_in[8];
  const float* cb   = (const float*)d_in[9];
  const float* dw1  = (const float*)d_in[10];
  const float* db1  = (const float*)d_in[11];
  const float* dw2  = (const float*)d_in[12];
  const float* db2  = (const float*)d_in[13];
  const float* dw3  = (const float*)d_in[14];
  const float* db3  = (const float*)d_in[15];
  float* out = (float*)d_out;

  char* p = (char*)d_ws;
  auto take = [&](size_t bytes) { char* q = p; p += (bytes + 255) & ~(size_t)255; return q; };

  float* accum = (float*)take(256);
  float* zsq  = (float*)take((size_t)BB * 4);
  float* cbsq = (float*)take((size_t)KK * 4);
  u16* x1p0 = (u16*)take((size_t)256 * HH * 2); u16* x1p1 = (u16*)take((size_t)256 * HH * 2);
  u16* x2p0 = (u16*)take((size_t)HH * HH * 2);  u16* x2p1 = (u16*)take((size_t)HH * HH * 2);
  u16* x3p0 = (u16*)take((size_t)HH * 768 * 2); u16* x3p1 = (u16*)take((size_t)HH * 768 * 2);
  float* Z  = (float*)take((size_t)BB * 256 * 4);
  float* H1 = (float*)take((size_t)BB * HH * 4);  // later: pv/pi partials, then D2
  float* H2 = (float*)take((size_t)BB * HH * 4);  // later: D1
  // Peak ws ~159 MB.

  float* pv = (float*)H1;                       // 8.4 MB (128 tiles x BB)
  int*   pi = (int*)(H1 + (size_t)128 * BB);    // 8.4 MB (H1 dead after enc2-read)
  float* D1 = H2;                               // H2 dead after enc3-read
  float* D2 = H1;                               // pv/pi dead after merge

  float* codesf = out + (size_t)3 * BB * 256;
  float* scalars = out + (size_t)3 * BB * 256 + BB;

  init_k<<<1, 1, 0, stream>>>(accum);

  transpose_split2<<<dim3(HH / 32, 256 / 32), dim3(32, 8), 0, stream>>>(dw1, x1p0, x1p1, 256, HH);
  transpose_split2<<<dim3(HH / 32, HH / 32), dim3(32, 8), 0, stream>>>(dw2, x2p0, x2p1, HH, HH);
  transpose_split2<<<dim3(768 / 32, HH / 32), dim3(32, 8), 0, stream>>>(dw3, x3p0, x3p1, HH, 768);

  // encoder — bit-exact np-f32 semantics
  sgemm_np<true, true><<<dim3(HH / 128, BB / 128), 256, 0, stream>>>(
      subj, rel_, obj, ew1, eb1, H1, BB, HH, 768);
  sgemm_np<true, false><<<dim3(HH / 128, BB / 128), 256, 0, stream>>>(
      H1, nullptr, nullptr, ew2, eb2, H2, BB, HH, HH);
  sgemm_np<false, false><<<dim3(256 / 128, BB / 128), 256, 0, stream>>>(
      H2, nullptr, nullptr, ew3, eb3, Z, BB, 256, HH);

  // row sums of squares — exact numpy pairwise trees
  rowsq_np<<<BB / 256, 256, 0, stream>>>(Z, zsq);
  rowsq_np<<<KK / 256, 256, 0, stream>>>(cb, cbsq);

  // f32-exact distance + argmin
  vqdist<<<dim3(KK / 128, BB / 128), 256, 0, stream>>>(Z, cb, zsq, cbsq, pv, pi);
  vq_merge3<<<BB / 256, 256, 0, stream>>>(pv, pi, codesf);

  zq_loss<<<(BB * 256) / 1024, 256, 0, stream>>>(codesf, cb, Z, accum);
  write_scalars<<<1, 1, 0, stream>>>(accum, scalars);

  // decoder
  gemm_dec<true, 2, 0><<<dim3(HH / 128, BB / 128), 256, 0, stream>>>(
      cb, codesf, x1p0, x1p1, db1, D1, BB, HH, 256);
  gemm_dec<true, 0, 0><<<dim3(HH / 128, BB / 128), 256, 0, stream>>>(
      D1, nullptr, x2p0, x2p1, db2, D2, BB, HH, HH);
  gemm_dec<false, 0, 1><<<dim3(768 / 128, BB / 128), 256, 0, stream>>>(
      D2, nullptr, x3p0, x3p1, db3, out, BB, 768, HH);
}